// Round 3
// baseline (88.171 us; speedup 1.0000x reference)
//
#include <hip/hip_runtime.h>

#define KITER 20

typedef __attribute__((ext_vector_type(8))) short short8;
typedef __attribute__((ext_vector_type(4))) short short4v;
typedef __attribute__((ext_vector_type(4))) float float4v;

static __device__ __forceinline__ short f2bf(float x) {
    unsigned u = __float_as_uint(x);
    unsigned r = (u + 0x7FFFu + ((u >> 16) & 1u)) >> 16;   // RNE
    return (short)r;
}
static __device__ __forceinline__ float bf2f(short h) {
    return __uint_as_float(((unsigned)(unsigned short)h) << 16);
}
struct BfPair { short hi, lo; };
static __device__ __forceinline__ BfPair split2(float x) {
    BfPair r;
    r.hi = f2bf(x);
    r.lo = f2bf(x - bf2f(r.hi));
    return r;
}

#define MF(c, a, b) c = __builtin_amdgcn_mfma_f32_16x16x32_bf16(a, b, c, 0, 0, 0)

// Block = 256 threads (4 waves), each thread owns one sample.
// Phi (48x48 matvec) done per-wave via MFMA 16x16x32 bf16 hi/lo split;
// VI (20 max-plus steps) stays thread-per-sample fp32.
__global__ __launch_bounds__(256, 4) void vpn_kernel(
    const float* __restrict__ obs,
    const float* __restrict__ W_phi,
    const float* __restrict__ b_phi,
    const float* __restrict__ W_logit,
    const float* __restrict__ b_logit,
    float* __restrict__ out, int B)
{
    // W fragments in MFMA-ready order: frag f = jt*2+kc (jt=j-tile 0..2, kc=k-chunk 0..1),
    // lane slot = 16B of 8 contiguous-k bf16. Zero-padded for k>=48.
    __shared__ __align__(16) unsigned short Wfh[6 * 64 * 8];   // 6144 B  (hi plane)
    __shared__ __align__(16) unsigned short Wfl[6 * 64 * 8];   // 6144 B  (lo plane)
    // per-wave transport buffer: ph rows stride 52 (16B aligned, 2-way banks);
    // also reused (stride 13) by the generic extraction path.
    __shared__ __align__(16) float buf[4][840];                // 13440 B

    const int t    = threadIdx.x;
    const int lane = t & 63;
    const int wave = t >> 6;
    const int smp  = blockIdx.x * 256 + t;
    const int wavebase = blockIdx.x * 256 + wave * 64;

    // ---------------- stage W fragments (once per block) ----------------
    #pragma unroll
    for (int m = 0; m < 3; ++m) {
        int H = t + m * 256;                 // 0..767 half-fragments
        int f = H >> 7, rem = H & 127;
        int L = rem >> 1, q = rem & 1;
        int jt = f >> 1, kc = f & 1;
        int j = jt * 16 + (L & 15), h = L >> 4;
        int k = kc * 32 + h * 8 + q * 4;
        float4 w = make_float4(0.f, 0.f, 0.f, 0.f);
        if (k < 48) w = *(const float4*)(W_phi + j * 48 + k);
        short4v hv, lv;
        BfPair s0 = split2(w.x), s1 = split2(w.y), s2 = split2(w.z), s3 = split2(w.w);
        hv[0] = s0.hi; lv[0] = s0.lo;
        hv[1] = s1.hi; lv[1] = s1.lo;
        hv[2] = s2.hi; lv[2] = s2.lo;
        hv[3] = s3.hi; lv[3] = s3.lo;
        int dst = (f * 64 + L) * 8 + q * 4;
        *(short4v*)&Wfh[dst] = hv;
        *(short4v*)&Wfl[dst] = lv;
    }

    // ---------------- own obs row: agent scan (o[] dies after this) -----
    int idx = 16;
    {
        float o1[16];
        const float4* o4 = (const float4*)(obs + (size_t)smp * 48);
        #pragma unroll
        for (int qq = 0; qq < 12; ++qq) {
            float4 v4 = o4[qq];
            // channel-1 entries are at flat index 3c+1
            int base = qq * 4;
            float vv[4] = {v4.x, v4.y, v4.z, v4.w};
            #pragma unroll
            for (int e = 0; e < 4; ++e) {
                int fi = base + e;
                if (fi % 3 == 1) o1[fi / 3] = vv[e];
            }
        }
        #pragma unroll
        for (int cell = 15; cell >= 0; --cell)
            if (o1[cell] != 0.0f) idx = cell;
    }
    const int ai = (idx == 16) ? 1 : (idx >> 2);
    const int aj = (idx == 16) ? 1 : (idx & 3);

    __syncthreads();   // W fragments ready

    // per-lane bias values (col j = lane&15 per j-tile)
    const int j15  = lane & 15;
    const int hgrp = lane >> 4;
    float bj0 = b_phi[j15], bj1 = b_phi[16 + j15], bj2 = b_phi[32 + j15];

    // hoist hi W-fragments into regs (24 VGPRs); lo re-read per group
    short8 wh[6];
    #pragma unroll
    for (int f = 0; f < 6; ++f)
        wh[f] = *(const short8*)&Wfh[(f * 64 + lane) * 8];

    // ---------------- Phi via MFMA, per 16-sample group ----------------
    float ph[48];
    #pragma unroll
    for (int g = 0; g < 4; ++g) {
        const float* ap = obs + (size_t)(wavebase + g * 16 + j15) * 48;
        // A chunk0: k = 8*hgrp..+8 ; chunk1: k = 32+8*hgrp (zero for hgrp>=2)
        float a0[8], a1[8];
        {
            float4 u0 = *(const float4*)(ap + 8 * hgrp);
            float4 u1 = *(const float4*)(ap + 8 * hgrp + 4);
            a0[0]=u0.x; a0[1]=u0.y; a0[2]=u0.z; a0[3]=u0.w;
            a0[4]=u1.x; a0[5]=u1.y; a0[6]=u1.z; a0[7]=u1.w;
            if (hgrp < 2) {
                float4 u2 = *(const float4*)(ap + 32 + 8 * hgrp);
                float4 u3 = *(const float4*)(ap + 36 + 8 * hgrp);
                a1[0]=u2.x; a1[1]=u2.y; a1[2]=u2.z; a1[3]=u2.w;
                a1[4]=u3.x; a1[5]=u3.y; a1[6]=u3.z; a1[7]=u3.w;
            } else {
                #pragma unroll
                for (int i = 0; i < 8; ++i) a1[i] = 0.0f;
            }
        }
        short8 a0h, a0l, a1h, a1l;
        #pragma unroll
        for (int i = 0; i < 8; ++i) {
            BfPair s0 = split2(a0[i]);
            BfPair s1 = split2(a1[i]);
            a0h[i] = s0.hi; a0l[i] = s0.lo;
            a1h[i] = s1.hi; a1l[i] = s1.lo;
        }

        float4v c0 = {0.f,0.f,0.f,0.f}, c1 = c0, c2 = c0;
        short8 wl;
        // kc = 0 (frags 0,2,4)
        wl = *(const short8*)&Wfl[(0*64 + lane)*8];
        MF(c0, a0h, wh[0]); MF(c0, a0h, wl); MF(c0, a0l, wh[0]);
        wl = *(const short8*)&Wfl[(2*64 + lane)*8];
        MF(c1, a0h, wh[2]); MF(c1, a0h, wl); MF(c1, a0l, wh[2]);
        wl = *(const short8*)&Wfl[(4*64 + lane)*8];
        MF(c2, a0h, wh[4]); MF(c2, a0h, wl); MF(c2, a0l, wh[4]);
        // kc = 1 (frags 1,3,5)
        wl = *(const short8*)&Wfl[(1*64 + lane)*8];
        MF(c0, a1h, wh[1]); MF(c0, a1h, wl); MF(c0, a1l, wh[1]);
        wl = *(const short8*)&Wfl[(3*64 + lane)*8];
        MF(c1, a1h, wh[3]); MF(c1, a1h, wl); MF(c1, a1l, wh[3]);
        wl = *(const short8*)&Wfl[(5*64 + lane)*8];
        MF(c2, a1h, wh[5]); MF(c2, a1h, wl); MF(c2, a1l, wh[5]);

        // C layout (m89): col = lane&15 (= j), row = 4*(lane>>4)+r (= sample in group)
        #pragma unroll
        for (int r = 0; r < 4; ++r) {
            int rowbase = (4 * hgrp + r) * 52;
            buf[wave][rowbase +  0 + j15] = c0[r] + bj0;
            buf[wave][rowbase + 16 + j15] = c1[r] + bj1;
            buf[wave][rowbase + 32 + j15] = c2[r] + bj2;
        }
        // readback: only the 16 lanes whose sample lives in group g
        if (hgrp == g) {
            #pragma unroll
            for (int qq = 0; qq < 12; ++qq)
                *(float4v*)&ph[qq * 4] = *(const float4v*)&buf[wave][j15 * 52 + qq * 4];
        }
    }

    // ---------------- VI: 20 max-plus steps (fp32, thread-local) --------
    float rin_[16], rout_[16], p_[16];
    #pragma unroll
    for (int c = 0; c < 16; ++c) {
        rin_[c]  = ph[3 * c + 0];
        rout_[c] = ph[3 * c + 1];
        p_[c]    = ph[3 * c + 2];
    }

    float v[16], nv[16];
    #pragma unroll
    for (int c = 0; c < 16; ++c) v[c] = 0.0f;

    // candidate f_d = p[cell]*v[nbr] + rin[nbr]; boundary dirs contribute 0;
    // nv = max(v, max_d(f_d) - rout[cell])
#define VI_STEP(SRC, DST)                                                     \
    {                                                                         \
        _Pragma("unroll")                                                     \
        for (int h = 0; h < 4; ++h) {                                         \
            _Pragma("unroll")                                                 \
            for (int w = 0; w < 4; ++w) {                                     \
                const int cell = h * 4 + w;                                   \
                const bool Ld = (w > 0), Rd = (w < 3), Ud = (h > 0), Dd = (h < 3); \
                float m = Ld ? fmaf(p_[cell], SRC[cell - 1], rin_[cell - 1]) : 0.0f; \
                if (Rd) m = fmaxf(m, fmaf(p_[cell], SRC[cell + 1], rin_[cell + 1])); \
                if (Ud) m = fmaxf(m, fmaf(p_[cell], SRC[cell - 4], rin_[cell - 4])); \
                if (Dd) m = fmaxf(m, fmaf(p_[cell], SRC[cell + 4], rin_[cell + 4])); \
                if (Ld && !(Rd && Ud && Dd)) m = fmaxf(m, 0.0f);              \
                DST[cell] = fmaxf(SRC[cell], m - rout_[cell]);                \
            }                                                                 \
        }                                                                     \
    }

    #pragma unroll 1
    for (int it = 0; it < KITER / 2; ++it) {
        VI_STEP(v, nv)
        VI_STEP(nv, v)
    }
#undef VI_STEP
    // final V (post-transpose): V[h][w] = v[w*4 + h]

    // ---------------- extraction + logit --------------------------------
    float li[36];
    const float* orow = obs + (size_t)smp * 48;
    if (idx == 0) {
        // agent at (0,0): in-bounds window cells are 0,1,4,5 (all static)
        float4 x0 = *(const float4*)(orow + 0);    // o0..o3
        float  x4 = orow[4], x5 = orow[5];
        float4 y0 = *(const float4*)(orow + 12);   // o12..o15
        float  y4 = orow[16], y5 = orow[17];
        #pragma unroll
        for (int i = 0; i < 36; ++i) li[i] = 0.0f;
        li[12] = x0.x; li[13] = x0.y; li[14] = x0.z;     // (1,1) cell 0
        li[15] = x0.w; li[16] = x4;   li[17] = x5;       // (1,2) cell 1
        li[21] = y0.x; li[22] = y0.y; li[23] = y0.z;     // (2,1) cell 4
        li[24] = y0.w; li[25] = y4;   li[26] = y5;       // (2,2) cell 5
        li[27 + 4] = v[0];   // (1,1) V[0][0]
        li[27 + 5] = v[4];   // (1,2) V[0][1]
        li[27 + 7] = v[1];   // (2,1) V[1][0]
        li[27 + 8] = v[5];   // (2,2) V[1][1]
    } else {
        // generic path (never taken for N(0,1) data, kept for correctness):
        // per-thread V window via reused buf region, obs re-read from global.
        #pragma unroll
        for (int h = 0; h < 4; ++h)
            #pragma unroll
            for (int w = 0; w < 4; ++w)
                buf[wave][lane * 13 + h * 4 + w] = v[w * 4 + h];
        #pragma unroll
        for (int a = 0; a < 3; ++a) {
            #pragma unroll
            for (int b = 0; b < 3; ++b) {
                const int hh = ai + a - 1, ww = aj + b - 1;
                const bool inb = (hh >= 0) && (hh < 4) && (ww >= 0) && (ww < 4);
                const int cl = inb ? (hh * 4 + ww) : 0;
                #pragma unroll
                for (int c = 0; c < 3; ++c)
                    li[a * 9 + b * 3 + c] = inb ? orow[cl * 3 + c] : 0.0f;
                li[27 + a * 3 + b] = inb ? buf[wave][lane * 13 + cl] : 0.0f;
            }
        }
    }

    float lg[4];
    #pragma unroll
    for (int a = 0; a < 4; ++a) {
        float acc = b_logit[a];
        #pragma unroll
        for (int m = 0; m < 36; ++m)
            acc = fmaf(li[m], W_logit[a * 36 + m], acc);
        lg[a] = acc;
    }
    if (smp < B)
        *(float4*)(out + (size_t)smp * 4) = make_float4(lg[0], lg[1], lg[2], lg[3]);
}

extern "C" void kernel_launch(void* const* d_in, const int* in_sizes, int n_in,
                              void* d_out, int out_size, void* d_ws, size_t ws_size,
                              hipStream_t stream) {
    const float* obs     = (const float*)d_in[0];
    const float* W_phi   = (const float*)d_in[1];
    const float* b_phi   = (const float*)d_in[2];
    const float* W_logit = (const float*)d_in[3];
    const float* b_logit = (const float*)d_in[4];
    float* out = (float*)d_out;
    (void)d_ws; (void)ws_size; (void)n_in;

    const int B = in_sizes[0] / 48;
    const int grid = B / 256;
    vpn_kernel<<<grid, 256, 0, stream>>>(obs, W_phi, b_phi, W_logit, b_logit, out, B);
}

// Round 4
// 28.636 us; speedup vs baseline: 3.0790x; 3.0790x over previous
//
#include <hip/hip_runtime.h>

#define KITER 20

typedef __attribute__((ext_vector_type(8))) short short8;
typedef __attribute__((ext_vector_type(4))) short short4v;
typedef __attribute__((ext_vector_type(4))) float float4v;

static __device__ __forceinline__ short f2bf(float x) {
    unsigned u = __float_as_uint(x);
    unsigned r = (u + 0x7FFFu + ((u >> 16) & 1u)) >> 16;   // RNE
    return (short)r;
}
static __device__ __forceinline__ float bf2f(short h) {
    return __uint_as_float(((unsigned)(unsigned short)h) << 16);
}
struct BfPair { short hi, lo; };
static __device__ __forceinline__ BfPair split2(float x) {   // RNE hi/lo (W staging only)
    BfPair r;
    r.hi = f2bf(x);
    r.lo = f2bf(x - bf2f(r.hi));
    return r;
}

static __device__ __forceinline__ unsigned cvt_pk_bf16(float a, float b) {
    unsigned r;
    asm("v_cvt_pk_bf16_f32 %0, %1, %2" : "=v"(r) : "v"(a), "v"(b));
    return r;   // low16 = bf16(a), high16 = bf16(b)
}

// truncation split of 8 f32 -> hi/lo bf16x8. hi = trunc (exact residual),
// lo = RNE(residual). err per element ~2^-17.
static __device__ __forceinline__ void split8(const float x[8], short8& hi, short8& lo) {
    union U { short8 s; unsigned u[4]; } H, L;
    #pragma unroll
    for (int q = 0; q < 4; ++q) {
        unsigned ue = __float_as_uint(x[2*q]);
        unsigned uo = __float_as_uint(x[2*q+1]);
        H.u[q] = (ue >> 16) | (uo & 0xFFFF0000u);
        float re = x[2*q]   - __uint_as_float(ue & 0xFFFF0000u);
        float ro = x[2*q+1] - __uint_as_float(uo & 0xFFFF0000u);
        L.u[q] = cvt_pk_bf16(re, ro);
    }
    hi = H.s; lo = L.s;
}

#define MF(c, a, b) c = __builtin_amdgcn_mfma_f32_16x16x32_bf16(a, b, c, 0, 0, 0)

// Block = 256 threads (4 waves), one sample per thread.
// Phi (48x48) via MFMA bf16 hi/lo split; VI thread-local fp32.
// launch_bounds(256,2): empirically caps VGPR ~128 (R3's (256,4) clamped to 64
// and spilled ~100MB of scratch traffic).
__global__ __launch_bounds__(256, 2) void vpn_kernel(
    const float* __restrict__ obs,
    const float* __restrict__ W_phi,
    const float* __restrict__ b_phi,
    const float* __restrict__ W_logit,
    const float* __restrict__ b_logit,
    float* __restrict__ out, int B)
{
    // W fragments, MFMA-ready: frag f = jt*2+kc, lane slot = 8 contiguous-k bf16.
    __shared__ __align__(16) unsigned short Wfh[6 * 64 * 8];   // 6144 B
    __shared__ __align__(16) unsigned short Wfl[6 * 64 * 8];   // 6144 B
    // per-wave ph transport (rows stride 52); reused by generic extraction.
    __shared__ __align__(16) float buf[4][840];                // 13440 B

    const int t    = threadIdx.x;
    const int lane = t & 63;
    const int wave = t >> 6;
    const int smp  = blockIdx.x * 256 + t;
    const int wavebase = blockIdx.x * 256 + wave * 64;

    // ---------------- stage W fragments (once per block) ----------------
    #pragma unroll
    for (int m = 0; m < 3; ++m) {
        int H = t + m * 256;                 // 0..767 half-fragments
        int f = H >> 7, rem = H & 127;
        int L = rem >> 1, q = rem & 1;
        int jt = f >> 1, kc = f & 1;
        int j = jt * 16 + (L & 15), h = L >> 4;
        int k = kc * 32 + h * 8 + q * 4;
        float4 w = make_float4(0.f, 0.f, 0.f, 0.f);
        if (k < 48) w = *(const float4*)(W_phi + j * 48 + k);
        short4v hv, lv;
        BfPair s0 = split2(w.x), s1 = split2(w.y), s2 = split2(w.z), s3 = split2(w.w);
        hv[0] = s0.hi; lv[0] = s0.lo;
        hv[1] = s1.hi; lv[1] = s1.lo;
        hv[2] = s2.hi; lv[2] = s2.lo;
        hv[3] = s3.hi; lv[3] = s3.lo;
        int dst = (f * 64 + L) * 8 + q * 4;
        *(short4v*)&Wfh[dst] = hv;
        *(short4v*)&Wfl[dst] = lv;
    }
    __syncthreads();   // W fragments ready

    const int j15  = lane & 15;
    const int hgrp = lane >> 4;
    const float bj0 = b_phi[j15], bj1 = b_phi[16 + j15], bj2 = b_phi[32 + j15];

    // ---------------- Phi via MFMA, per 16-sample group ------------------
    // ph[48] = this thread's sample features (filled in group hgrp-of-self).
    float ph[48];
    #pragma unroll
    for (int g = 0; g < 4; ++g) {
        const float* ap = obs + (size_t)(wavebase + g * 16 + j15) * 48 + 8 * hgrp;
        float a0[8], a1[8];
        {
            float4 u0 = *(const float4*)(ap);
            float4 u1 = *(const float4*)(ap + 4);
            a0[0]=u0.x; a0[1]=u0.y; a0[2]=u0.z; a0[3]=u0.w;
            a0[4]=u1.x; a0[5]=u1.y; a0[6]=u1.z; a0[7]=u1.w;
            if (hgrp < 2) {
                float4 u2 = *(const float4*)(ap + 32);
                float4 u3 = *(const float4*)(ap + 36);
                a1[0]=u2.x; a1[1]=u2.y; a1[2]=u2.z; a1[3]=u2.w;
                a1[4]=u3.x; a1[5]=u3.y; a1[6]=u3.z; a1[7]=u3.w;
            } else {
                #pragma unroll
                for (int i = 0; i < 8; ++i) a1[i] = 0.0f;
            }
        }
        short8 a0h, a0l, a1h, a1l;
        split8(a0, a0h, a0l);
        split8(a1, a1h, a1l);

        float4v c0 = {0.f,0.f,0.f,0.f}, c1 = c0, c2 = c0;
        short8 wh, wl;
        // kc = 0 (frags 0,2,4)
        wh = *(const short8*)&Wfh[(0*64 + lane)*8];
        wl = *(const short8*)&Wfl[(0*64 + lane)*8];
        MF(c0, a0h, wh); MF(c0, a0h, wl); MF(c0, a0l, wh);
        wh = *(const short8*)&Wfh[(2*64 + lane)*8];
        wl = *(const short8*)&Wfl[(2*64 + lane)*8];
        MF(c1, a0h, wh); MF(c1, a0h, wl); MF(c1, a0l, wh);
        wh = *(const short8*)&Wfh[(4*64 + lane)*8];
        wl = *(const short8*)&Wfl[(4*64 + lane)*8];
        MF(c2, a0h, wh); MF(c2, a0h, wl); MF(c2, a0l, wh);
        // kc = 1 (frags 1,3,5)
        wh = *(const short8*)&Wfh[(1*64 + lane)*8];
        wl = *(const short8*)&Wfl[(1*64 + lane)*8];
        MF(c0, a1h, wh); MF(c0, a1h, wl); MF(c0, a1l, wh);
        wh = *(const short8*)&Wfh[(3*64 + lane)*8];
        wl = *(const short8*)&Wfl[(3*64 + lane)*8];
        MF(c1, a1h, wh); MF(c1, a1h, wl); MF(c1, a1l, wh);
        wh = *(const short8*)&Wfh[(5*64 + lane)*8];
        wl = *(const short8*)&Wfl[(5*64 + lane)*8];
        MF(c2, a1h, wh); MF(c2, a1h, wl); MF(c2, a1l, wh);

        // C layout (m89): col = lane&15 (=j), row = 4*hgrp + r (= sample in group)
        #pragma unroll
        for (int r = 0; r < 4; ++r) {
            int rowbase = (4 * hgrp + r) * 52;
            buf[wave][rowbase +  0 + j15] = c0[r] + bj0;
            buf[wave][rowbase + 16 + j15] = c1[r] + bj1;
            buf[wave][rowbase + 32 + j15] = c2[r] + bj2;
        }
        if (hgrp == g) {   // this quarter's samples were just computed
            #pragma unroll
            for (int qq = 0; qq < 12; ++qq)
                *(float4v*)&ph[qq * 4] = *(const float4v*)&buf[wave][j15 * 52 + qq * 4];
        }
    }

    // ---------------- VI: 20 max-plus steps (fp32, thread-local) --------
    float rin_[16], rout_[16], p_[16];
    #pragma unroll
    for (int c = 0; c < 16; ++c) {
        rin_[c]  = ph[3 * c + 0];
        rout_[c] = ph[3 * c + 1];
        p_[c]    = ph[3 * c + 2];
    }

    float v[16], nv[16];
    #pragma unroll
    for (int c = 0; c < 16; ++c) v[c] = 0.0f;

#define VI_STEP(SRC, DST)                                                     \
    {                                                                         \
        _Pragma("unroll")                                                     \
        for (int h = 0; h < 4; ++h) {                                         \
            _Pragma("unroll")                                                 \
            for (int w = 0; w < 4; ++w) {                                     \
                const int cell = h * 4 + w;                                   \
                const bool Ld = (w > 0), Rd = (w < 3), Ud = (h > 0), Dd = (h < 3); \
                float m = Ld ? fmaf(p_[cell], SRC[cell - 1], rin_[cell - 1]) : 0.0f; \
                if (Rd) m = fmaxf(m, fmaf(p_[cell], SRC[cell + 1], rin_[cell + 1])); \
                if (Ud) m = fmaxf(m, fmaf(p_[cell], SRC[cell - 4], rin_[cell - 4])); \
                if (Dd) m = fmaxf(m, fmaf(p_[cell], SRC[cell + 4], rin_[cell + 4])); \
                if (Ld && !(Rd && Ud && Dd)) m = fmaxf(m, 0.0f);              \
                DST[cell] = fmaxf(SRC[cell], m - rout_[cell]);                \
            }                                                                 \
        }                                                                     \
    }

    #pragma unroll 1
    for (int it = 0; it < KITER / 2; ++it) {
        VI_STEP(v, nv)
        VI_STEP(nv, v)
    }
#undef VI_STEP
    // final V (post-transpose): V[h][w] = v[w*4 + h]

    // ---------------- end: own-row read, agent scan, extraction, logit ---
    const float* orow = obs + (size_t)smp * 48;
    float o[48];
    {
        const float4* o4 = (const float4*)orow;
        #pragma unroll
        for (int qq = 0; qq < 12; ++qq) {
            float4 u = o4[qq];
            o[4*qq+0] = u.x; o[4*qq+1] = u.y; o[4*qq+2] = u.z; o[4*qq+3] = u.w;
        }
    }
    int idx = 16;
    #pragma unroll
    for (int cell = 15; cell >= 0; --cell)
        if (o[cell * 3 + 1] != 0.0f) idx = cell;

    float lg[4];
    if (idx == 0) {
        // agent at (0,0): nonzero logit_in terms are obs cells 0,1,4,5 and
        // V[0][0],V[0][1],V[1][0],V[1][1] -> direct 16-term dot per action.
        #pragma unroll
        for (int a = 0; a < 4; ++a) {
            const float* Wl = W_logit + a * 36;
            float acc = b_logit[a];
            acc = fmaf(o[0],  Wl[12], acc);
            acc = fmaf(o[1],  Wl[13], acc);
            acc = fmaf(o[2],  Wl[14], acc);
            acc = fmaf(o[3],  Wl[15], acc);
            acc = fmaf(o[4],  Wl[16], acc);
            acc = fmaf(o[5],  Wl[17], acc);
            acc = fmaf(o[12], Wl[21], acc);
            acc = fmaf(o[13], Wl[22], acc);
            acc = fmaf(o[14], Wl[23], acc);
            acc = fmaf(o[15], Wl[24], acc);
            acc = fmaf(o[16], Wl[25], acc);
            acc = fmaf(o[17], Wl[26], acc);
            acc = fmaf(v[0],  Wl[31], acc);
            acc = fmaf(v[4],  Wl[32], acc);
            acc = fmaf(v[1],  Wl[34], acc);
            acc = fmaf(v[5],  Wl[35], acc);
            lg[a] = acc;
        }
    } else {
        // generic path (not taken for N(0,1) data; kept for correctness).
        const int ai = (idx == 16) ? 1 : (idx >> 2);
        const int aj = (idx == 16) ? 1 : (idx & 3);
        #pragma unroll
        for (int h = 0; h < 4; ++h)
            #pragma unroll
            for (int w = 0; w < 4; ++w)
                buf[wave][lane * 13 + h * 4 + w] = v[w * 4 + h];   // transposed V
        float li[36];
        #pragma unroll
        for (int a = 0; a < 3; ++a) {
            #pragma unroll
            for (int b = 0; b < 3; ++b) {
                const int hh = ai + a - 1, ww = aj + b - 1;
                const bool inb = (hh >= 0) && (hh < 4) && (ww >= 0) && (ww < 4);
                const int cl = inb ? (hh * 4 + ww) : 0;
                #pragma unroll
                for (int c = 0; c < 3; ++c)
                    li[a * 9 + b * 3 + c] = inb ? orow[cl * 3 + c] : 0.0f;
                li[27 + a * 3 + b] = inb ? buf[wave][lane * 13 + cl] : 0.0f;
            }
        }
        #pragma unroll
        for (int a = 0; a < 4; ++a) {
            float acc = b_logit[a];
            #pragma unroll
            for (int m = 0; m < 36; ++m)
                acc = fmaf(li[m], W_logit[a * 36 + m], acc);
            lg[a] = acc;
        }
    }

    *(float4*)(out + (size_t)smp * 4) = make_float4(lg[0], lg[1], lg[2], lg[3]);
}

extern "C" void kernel_launch(void* const* d_in, const int* in_sizes, int n_in,
                              void* d_out, int out_size, void* d_ws, size_t ws_size,
                              hipStream_t stream) {
    const float* obs     = (const float*)d_in[0];
    const float* W_phi   = (const float*)d_in[1];
    const float* b_phi   = (const float*)d_in[2];
    const float* W_logit = (const float*)d_in[3];
    const float* b_logit = (const float*)d_in[4];
    float* out = (float*)d_out;
    (void)d_ws; (void)ws_size; (void)n_in;

    const int B = in_sizes[0] / 48;
    const int grid = B / 256;
    vpn_kernel<<<grid, 256, 0, stream>>>(obs, W_phi, b_phi, W_logit, b_logit, out, B);
}

// Round 5
// 28.341 us; speedup vs baseline: 3.1111x; 1.0104x over previous
//
#include <hip/hip_runtime.h>

#define KITER 20

typedef __attribute__((ext_vector_type(8))) short short8;
typedef __attribute__((ext_vector_type(4))) short short4v;
typedef __attribute__((ext_vector_type(4))) float float4v;

static __device__ __forceinline__ short f2bf(float x) {
    unsigned u = __float_as_uint(x);
    unsigned r = (u + 0x7FFFu + ((u >> 16) & 1u)) >> 16;   // RNE
    return (short)r;
}
static __device__ __forceinline__ float bf2f(short h) {
    return __uint_as_float(((unsigned)(unsigned short)h) << 16);
}
struct BfPair { short hi, lo; };
static __device__ __forceinline__ BfPair split2(float x) {   // RNE hi/lo (W staging only)
    BfPair r;
    r.hi = f2bf(x);
    r.lo = f2bf(x - bf2f(r.hi));
    return r;
}

static __device__ __forceinline__ unsigned cvt_pk_bf16(float a, float b) {
    unsigned r;
    asm("v_cvt_pk_bf16_f32 %0, %1, %2" : "=v"(r) : "v"(a), "v"(b));
    return r;   // low16 = bf16(a), high16 = bf16(b)
}

// truncation split of 8 f32 -> hi/lo bf16x8. hi = trunc (exact residual),
// lo = RNE(residual). err per element ~2^-17.
static __device__ __forceinline__ void split8(const float x[8], short8& hi, short8& lo) {
    union U { short8 s; unsigned u[4]; } H, L;
    #pragma unroll
    for (int q = 0; q < 4; ++q) {
        unsigned ue = __float_as_uint(x[2*q]);
        unsigned uo = __float_as_uint(x[2*q+1]);
        H.u[q] = (ue >> 16) | (uo & 0xFFFF0000u);
        float re = x[2*q]   - __uint_as_float(ue & 0xFFFF0000u);
        float ro = x[2*q+1] - __uint_as_float(uo & 0xFFFF0000u);
        L.u[q] = cvt_pk_bf16(re, ro);
    }
    hi = H.s; lo = L.s;
}

#define MF(c, a, b) c = __builtin_amdgcn_mfma_f32_16x16x32_bf16(a, b, c, 0, 0, 0)

// Block = 256 threads (4 waves), one sample per thread.
// Phi (48x48) via MFMA bf16 hi/lo split; VI thread-local fp32.
// launch_bounds(256,3): cap ~160 VGPR -> >=3 blocks/CU resident (R4's (256,2)
// left only 2 waves/SIMD and was stall-bound; R3's (256,4) split the unified
// file 64/64 and spilled ~100MB).
__global__ __launch_bounds__(256, 3) void vpn_kernel(
    const float* __restrict__ obs,
    const float* __restrict__ W_phi,
    const float* __restrict__ b_phi,
    const float* __restrict__ W_logit,
    const float* __restrict__ b_logit,
    float* __restrict__ out, int B)
{
    // W fragments, MFMA-ready: frag f = jt*2+kc, lane slot = 8 contiguous-k bf16.
    __shared__ __align__(16) unsigned short Wfh[6 * 64 * 8];   // 6144 B
    __shared__ __align__(16) unsigned short Wfl[6 * 64 * 8];   // 6144 B
    // per-wave ph transport (rows stride 52); reused by generic extraction.
    __shared__ __align__(16) float buf[4][840];                // 13440 B

    const int t    = threadIdx.x;
    const int lane = t & 63;
    const int wave = t >> 6;
    const int smp  = blockIdx.x * 256 + t;
    const int wavebase = blockIdx.x * 256 + wave * 64;

    // ---------------- stage W fragments (once per block) ----------------
    #pragma unroll
    for (int m = 0; m < 3; ++m) {
        int H = t + m * 256;                 // 0..767 half-fragments
        int f = H >> 7, rem = H & 127;
        int L = rem >> 1, q = rem & 1;
        int jt = f >> 1, kc = f & 1;
        int j = jt * 16 + (L & 15), h = L >> 4;
        int k = kc * 32 + h * 8 + q * 4;
        float4 w = make_float4(0.f, 0.f, 0.f, 0.f);
        if (k < 48) w = *(const float4*)(W_phi + j * 48 + k);
        short4v hv, lv;
        BfPair s0 = split2(w.x), s1 = split2(w.y), s2 = split2(w.z), s3 = split2(w.w);
        hv[0] = s0.hi; lv[0] = s0.lo;
        hv[1] = s1.hi; lv[1] = s1.lo;
        hv[2] = s2.hi; lv[2] = s2.lo;
        hv[3] = s3.hi; lv[3] = s3.lo;
        int dst = (f * 64 + L) * 8 + q * 4;
        *(short4v*)&Wfh[dst] = hv;
        *(short4v*)&Wfl[dst] = lv;
    }
    __syncthreads();   // W fragments ready

    const int j15  = lane & 15;
    const int hgrp = lane >> 4;
    const float bj0 = b_phi[j15], bj1 = b_phi[16 + j15], bj2 = b_phi[32 + j15];

    // ---------------- Phi via MFMA, per 16-sample group ------------------
    float ph[48];
    #pragma unroll
    for (int g = 0; g < 4; ++g) {
        const float* ap = obs + (size_t)(wavebase + g * 16 + j15) * 48 + 8 * hgrp;
        float a0[8], a1[8];
        {
            float4 u0 = *(const float4*)(ap);
            float4 u1 = *(const float4*)(ap + 4);
            a0[0]=u0.x; a0[1]=u0.y; a0[2]=u0.z; a0[3]=u0.w;
            a0[4]=u1.x; a0[5]=u1.y; a0[6]=u1.z; a0[7]=u1.w;
            if (hgrp < 2) {
                float4 u2 = *(const float4*)(ap + 32);
                float4 u3 = *(const float4*)(ap + 36);
                a1[0]=u2.x; a1[1]=u2.y; a1[2]=u2.z; a1[3]=u2.w;
                a1[4]=u3.x; a1[5]=u3.y; a1[6]=u3.z; a1[7]=u3.w;
            } else {
                #pragma unroll
                for (int i = 0; i < 8; ++i) a1[i] = 0.0f;
            }
        }
        short8 a0h, a0l, a1h, a1l;
        split8(a0, a0h, a0l);
        split8(a1, a1h, a1l);

        float4v c0 = {0.f,0.f,0.f,0.f}, c1 = c0, c2 = c0;
        short8 wh, wl;
        // kc = 0 (frags 0,2,4)
        wh = *(const short8*)&Wfh[(0*64 + lane)*8];
        wl = *(const short8*)&Wfl[(0*64 + lane)*8];
        MF(c0, a0h, wh); MF(c0, a0h, wl); MF(c0, a0l, wh);
        wh = *(const short8*)&Wfh[(2*64 + lane)*8];
        wl = *(const short8*)&Wfl[(2*64 + lane)*8];
        MF(c1, a0h, wh); MF(c1, a0h, wl); MF(c1, a0l, wh);
        wh = *(const short8*)&Wfh[(4*64 + lane)*8];
        wl = *(const short8*)&Wfl[(4*64 + lane)*8];
        MF(c2, a0h, wh); MF(c2, a0h, wl); MF(c2, a0l, wh);
        // kc = 1 (frags 1,3,5)
        wh = *(const short8*)&Wfh[(1*64 + lane)*8];
        wl = *(const short8*)&Wfl[(1*64 + lane)*8];
        MF(c0, a1h, wh); MF(c0, a1h, wl); MF(c0, a1l, wh);
        wh = *(const short8*)&Wfh[(3*64 + lane)*8];
        wl = *(const short8*)&Wfl[(3*64 + lane)*8];
        MF(c1, a1h, wh); MF(c1, a1h, wl); MF(c1, a1l, wh);
        wh = *(const short8*)&Wfh[(5*64 + lane)*8];
        wl = *(const short8*)&Wfl[(5*64 + lane)*8];
        MF(c2, a1h, wh); MF(c2, a1h, wl); MF(c2, a1l, wh);

        // C layout (m89): col = lane&15 (=j), row = 4*hgrp + r (= sample in group)
        #pragma unroll
        for (int r = 0; r < 4; ++r) {
            int rowbase = (4 * hgrp + r) * 52;
            buf[wave][rowbase +  0 + j15] = c0[r] + bj0;
            buf[wave][rowbase + 16 + j15] = c1[r] + bj1;
            buf[wave][rowbase + 32 + j15] = c2[r] + bj2;
        }
        if (hgrp == g) {   // this quarter's samples were just computed
            #pragma unroll
            for (int qq = 0; qq < 12; ++qq)
                *(float4v*)&ph[qq * 4] = *(const float4v*)&buf[wave][j15 * 52 + qq * 4];
        }
    }

    // ---------------- prefetch own-row extraction data (hidden under VI) -
    const float* orow = obs + (size_t)smp * 48;
    float4 q0 = *(const float4*)(orow + 0);    // o0..o3
    float4 q1 = *(const float4*)(orow + 4);    // o4..o7
    float4 q3 = *(const float4*)(orow + 12);   // o12..o15
    float4 q4 = *(const float4*)(orow + 16);   // o16..o19
    float s10 = orow[10], s22 = orow[22], s25 = orow[25], s28 = orow[28];
    float s31 = orow[31], s34 = orow[34], s37 = orow[37], s40 = orow[40];
    float s43 = orow[43], s46 = orow[46];
    // channel-1 values for cells 0..15:
    float ch1[16] = { q0.y, q1.x, q1.w, s10, q3.y, q4.x, q4.w, s22,
                      s25,  s28,  s31,  s34, s37,  s40,  s43,  s46 };
    int idx = 16;
    #pragma unroll
    for (int cell = 15; cell >= 0; --cell)
        if (ch1[cell] != 0.0f) idx = cell;

    // ---------------- VI: 20 max-plus steps (fp32, thread-local) --------
    float rin_[16], rout_[16], p_[16];
    #pragma unroll
    for (int c = 0; c < 16; ++c) {
        rin_[c]  = ph[3 * c + 0];
        rout_[c] = ph[3 * c + 1];
        p_[c]    = ph[3 * c + 2];
    }

    float v[16], nv[16];
    #pragma unroll
    for (int c = 0; c < 16; ++c) v[c] = 0.0f;

#define VI_STEP(SRC, DST)                                                     \
    {                                                                         \
        _Pragma("unroll")                                                     \
        for (int h = 0; h < 4; ++h) {                                         \
            _Pragma("unroll")                                                 \
            for (int w = 0; w < 4; ++w) {                                     \
                const int cell = h * 4 + w;                                   \
                const bool Ld = (w > 0), Rd = (w < 3), Ud = (h > 0), Dd = (h < 3); \
                float m = Ld ? fmaf(p_[cell], SRC[cell - 1], rin_[cell - 1]) : 0.0f; \
                if (Rd) m = fmaxf(m, fmaf(p_[cell], SRC[cell + 1], rin_[cell + 1])); \
                if (Ud) m = fmaxf(m, fmaf(p_[cell], SRC[cell - 4], rin_[cell - 4])); \
                if (Dd) m = fmaxf(m, fmaf(p_[cell], SRC[cell + 4], rin_[cell + 4])); \
                if (Ld && !(Rd && Ud && Dd)) m = fmaxf(m, 0.0f);              \
                DST[cell] = fmaxf(SRC[cell], m - rout_[cell]);                \
            }                                                                 \
        }                                                                     \
    }

    #pragma unroll 1
    for (int it = 0; it < KITER / 2; ++it) {
        VI_STEP(v, nv)
        VI_STEP(nv, v)
    }
#undef VI_STEP
    // final V (post-transpose): V[h][w] = v[w*4 + h]

    // ---------------- extraction + logit --------------------------------
    float lg[4];
    if (idx == 0) {
        // agent at (0,0): nonzero logit_in terms are obs cells 0,1,4,5 and
        // V[0][0],V[0][1],V[1][0],V[1][1] -> direct 16-term dot per action.
        #pragma unroll
        for (int a = 0; a < 4; ++a) {
            const float* Wl = W_logit + a * 36;
            float acc = b_logit[a];
            acc = fmaf(q0.x, Wl[12], acc);
            acc = fmaf(q0.y, Wl[13], acc);
            acc = fmaf(q0.z, Wl[14], acc);
            acc = fmaf(q0.w, Wl[15], acc);
            acc = fmaf(q1.x, Wl[16], acc);
            acc = fmaf(q1.y, Wl[17], acc);
            acc = fmaf(q3.x, Wl[21], acc);
            acc = fmaf(q3.y, Wl[22], acc);
            acc = fmaf(q3.z, Wl[23], acc);
            acc = fmaf(q3.w, Wl[24], acc);
            acc = fmaf(q4.x, Wl[25], acc);
            acc = fmaf(q4.y, Wl[26], acc);
            acc = fmaf(v[0], Wl[31], acc);
            acc = fmaf(v[4], Wl[32], acc);
            acc = fmaf(v[1], Wl[34], acc);
            acc = fmaf(v[5], Wl[35], acc);
            lg[a] = acc;
        }
    } else {
        // generic path (not taken for N(0,1) data; kept for correctness).
        const int ai = (idx == 16) ? 1 : (idx >> 2);
        const int aj = (idx == 16) ? 1 : (idx & 3);
        #pragma unroll
        for (int h = 0; h < 4; ++h)
            #pragma unroll
            for (int w = 0; w < 4; ++w)
                buf[wave][lane * 13 + h * 4 + w] = v[w * 4 + h];   // transposed V
        float li[36];
        #pragma unroll
        for (int a = 0; a < 3; ++a) {
            #pragma unroll
            for (int b = 0; b < 3; ++b) {
                const int hh = ai + a - 1, ww = aj + b - 1;
                const bool inb = (hh >= 0) && (hh < 4) && (ww >= 0) && (ww < 4);
                const int cl = inb ? (hh * 4 + ww) : 0;
                #pragma unroll
                for (int c = 0; c < 3; ++c)
                    li[a * 9 + b * 3 + c] = inb ? orow[cl * 3 + c] : 0.0f;
                li[27 + a * 3 + b] = inb ? buf[wave][lane * 13 + cl] : 0.0f;
            }
        }
        #pragma unroll
        for (int a = 0; a < 4; ++a) {
            float acc = b_logit[a];
            #pragma unroll
            for (int m = 0; m < 36; ++m)
                acc = fmaf(li[m], W_logit[a * 36 + m], acc);
            lg[a] = acc;
        }
    }

    *(float4*)(out + (size_t)smp * 4) = make_float4(lg[0], lg[1], lg[2], lg[3]);
}

extern "C" void kernel_launch(void* const* d_in, const int* in_sizes, int n_in,
                              void* d_out, int out_size, void* d_ws, size_t ws_size,
                              hipStream_t stream) {
    const float* obs     = (const float*)d_in[0];
    const float* W_phi   = (const float*)d_in[1];
    const float* b_phi   = (const float*)d_in[2];
    const float* W_logit = (const float*)d_in[3];
    const float* b_logit = (const float*)d_in[4];
    float* out = (float*)d_out;
    (void)d_ws; (void)ws_size; (void)n_in;

    const int B = in_sizes[0] / 48;
    const int grid = B / 256;
    vpn_kernel<<<grid, 256, 0, stream>>>(obs, W_phi, b_phi, W_logit, b_logit, out, B);
}